// Round 9
// baseline (162.139 us; speedup 1.0000x reference)
//
#include <hip/hip_runtime.h>

// Attention fwd: x@Wqkv^T -> flash attn -> @Wproj^T.  bf16 MFMA pipeline, fp32 accum.
// B=2 N=2048 C=768 H=12 Dh=64.

typedef __bf16 bf16;
typedef __attribute__((ext_vector_type(8))) __bf16 bf16x8;
typedef __attribute__((ext_vector_type(4))) __bf16 bf16x4;
typedef __attribute__((ext_vector_type(2))) __bf16 bf16x2;
typedef __attribute__((ext_vector_type(4))) float f32x4;

typedef __attribute__((address_space(1))) void gvoid;
typedef __attribute__((address_space(3))) void lvoid;

__device__ __forceinline__ void gload16(const void* g, void* l) {
  __builtin_amdgcn_global_load_lds((gvoid*)g, (lvoid*)l, 16, 0, 0);
}

// ---------------- fp32 -> bf16 conversion (x, W_qkv, W_proj) ----------------
__global__ __launch_bounds__(256) void cvt3(const float* __restrict__ x,
                                            const float* __restrict__ wq,
                                            const float* __restrict__ wp,
                                            bf16* __restrict__ xb,
                                            bf16* __restrict__ wqb,
                                            bf16* __restrict__ wpb) {
  const int N1 = 786432, N2 = 442368, N3 = 147456;  // float4 counts
  int i = blockIdx.x * 256 + threadIdx.x;
  const int stride = gridDim.x * 256;
  const int total = N1 + N2 + N3;
  for (; i < total; i += stride) {
    const float* src; bf16* dst; int j;
    if (i < N1)           { src = x;  dst = xb;  j = i; }
    else if (i < N1 + N2) { src = wq; dst = wqb; j = i - N1; }
    else                  { src = wp; dst = wpb; j = i - N1 - N2; }
    float4 v = ((const float4*)src)[j];
    bf16x4 o = { (bf16)v.x, (bf16)v.y, (bf16)v.z, (bf16)v.w };
    *(bf16x4*)(dst + (long)j * 4) = o;
  }
}

// ---------------- NT GEMM: C[M,N] = A[M,K] * B[N,K]^T, bf16 in, fp32 accum -----
template <typename OutT, int BM, int BN>
__global__ __launch_bounds__(256, 3) void gemm_nt(const bf16* __restrict__ A,
                                                  const bf16* __restrict__ B,
                                                  OutT* __restrict__ C,
                                                  int K, int lda, int ldb, int ldc,
                                                  int mtiles) {
  constexpr int MI = BM / 32;
  constexpr int NI = BN / 32;
  constexpr int LDSA = BM * 128;
  constexpr int LDSB = BN * 128;
  __shared__ __align__(16) char smem[2 * (LDSA + LDSB)];

  const int tid  = threadIdx.x;
  const int lane = tid & 63;
  const int w    = tid >> 6;
  const int wm   = w >> 1, wn = w & 1;
  const int l15  = lane & 15;
  const int l4   = lane >> 4;
  const int m0   = (blockIdx.x % mtiles) * BM;
  const int n0   = (blockIdx.x / mtiles) * BN;
  const int nt   = K >> 6;

  f32x4 acc[MI][NI] = {};

  auto stage = [&](int buf, int t) {
    const int k0 = t << 6;
    char* sA = smem + buf * (LDSA + LDSB);
    char* sB = sA + LDSA;
#pragma unroll
    for (int i = 0; i < BM * 8 / 256; ++i) {
      const int s = i * 256 + tid;
      const int r = s >> 3;
      const int c = (s & 7) ^ (r & 7);
      gload16(A + (long)(m0 + r) * lda + k0 + c * 8, sA + s * 16);
    }
#pragma unroll
    for (int i = 0; i < BN * 8 / 256; ++i) {
      const int s = i * 256 + tid;
      const int r = s >> 3;
      const int c = (s & 7) ^ (r & 7);
      gload16(B + (long)(n0 + r) * ldb + k0 + c * 8, sB + s * 16);
    }
  };

  auto compute = [&](int buf) {
    const char* sA = smem + buf * (LDSA + LDSB);
    const char* sB = sA + LDSA;
#pragma unroll
    for (int kk = 0; kk < 2; ++kk) {
      bf16x8 a[MI], bb[NI];
#pragma unroll
      for (int mi = 0; mi < MI; ++mi) {
        const int row = wm * (BM / 2) + mi * 16 + l15;
        a[mi] = *(const bf16x8*)(sA + row * 128 + (((kk * 4 + l4) ^ (row & 7)) << 4));
      }
#pragma unroll
      for (int ni = 0; ni < NI; ++ni) {
        const int row = wn * (BN / 2) + ni * 16 + l15;
        bb[ni] = *(const bf16x8*)(sB + row * 128 + (((kk * 4 + l4) ^ (row & 7)) << 4));
      }
#pragma unroll
      for (int mi = 0; mi < MI; ++mi)
#pragma unroll
        for (int ni = 0; ni < NI; ++ni)
          acc[mi][ni] = __builtin_amdgcn_mfma_f32_16x16x32_bf16(a[mi], bb[ni], acc[mi][ni], 0, 0, 0);
    }
  };

  stage(0, 0);
  __syncthreads();
  for (int t = 0; t < nt; ++t) {
    if (t + 1 < nt) stage((t + 1) & 1, t + 1);
    compute(t & 1);
    __syncthreads();
  }

#pragma unroll
  for (int mi = 0; mi < MI; ++mi)
#pragma unroll
    for (int ni = 0; ni < NI; ++ni)
#pragma unroll
      for (int r = 0; r < 4; ++r) {
        const int row = m0 + wm * (BM / 2) + mi * 16 + l4 * 4 + r;
        const int col = n0 + wn * (BN / 2) + ni * 16 + l15;
        C[(long)row * ldc + col] = (OutT)acc[mi][ni][r];
      }
}

// ---------------- flash attention fwd (K through LDS, KV split across blocks) -
// grid (32 qtiles, 24 bh, 2 halves); block 256 = 4 waves, wave owns 16 q-rows.
// Half z processes kv [z*1024, z*1024+1024) = 16 tiles; per-block structure
// identical to the R7-verified kernel.  Each half writes l-normalized partial
// O (bf16) + merge weight w = m + log2(l): half 0 -> ob, half 1 -> pb1.
__global__ __launch_bounds__(256, 5) void attn_fwd(const bf16* __restrict__ qkv,
                                                   bf16* __restrict__ ob,
                                                   bf16* __restrict__ pb1,
                                                   float* __restrict__ wbuf) {
  __shared__ __align__(16) char Ks[16384];  // 2 bufs x K[64 rows][128B] swizzled
  __shared__ __align__(16) char Vs[16384];  // 2 bufs x Vt[64 d][128B kv] swizzled
  const int tid  = threadIdx.x;
  const int lane = tid & 63;
  const int wv   = tid >> 6;
  const int l15  = lane & 15;
  const int l4   = lane >> 4;
  const int b    = blockIdx.y / 12;
  const int h    = blockIdx.y % 12;
  const int z    = blockIdx.z;
  const int q0   = blockIdx.x * 64;
  const unsigned base = (unsigned)b * 2048u * 2304u;
  const int h64  = h * 64;
  const unsigned VSTEP = 64u * 2304u;
  const unsigned kvoff = (unsigned)(z * 1024) * 2304u;

  // Q fragments, pre-scaled by SCALE*log2(e) = 0.125 * 1.4426950
  bf16x8 qf[2];
  {
    const bf16* qp = qkv + base + (unsigned)(q0 + wv * 16 + l15) * 2304u + h64 + l4 * 8;
#pragma unroll
    for (int kk = 0; kk < 2; ++kk) {
      bf16x8 t = *(const bf16x8*)(qp + kk * 32);
#pragma unroll
      for (int j = 0; j < 8; ++j) qf[kk][j] = (bf16)((float)t[j] * 0.18033688f);
    }
  }

  // K staging: 2 rounds x 256 threads of 16B chunks; slot s -> row=s>>3, c'=s&7.
  const int krow0 = tid >> 3;
  const int kc0   = (tid & 7) ^ (krow0 & 7);
  const int krow1 = (256 + tid) >> 3;
  const int kc1   = (tid & 7) ^ (krow1 & 7);
  unsigned koff0 = base + kvoff + (unsigned)krow0 * 2304u + 768u + h64 + kc0 * 8;
  unsigned koff1 = base + kvoff + (unsigned)krow1 * 2304u + 768u + h64 + kc1 * 8;

  auto k_stage = [&](int buf) {
    gload16(qkv + koff0, Ks + buf * 8192 + tid * 16);
    gload16(qkv + koff1, Ks + buf * 8192 + 4096 + tid * 16);
    koff0 += VSTEP;
    koff1 += VSTEP;
  };

  // V staging: thread -> kv pair p = tid&31 (rows 2p,2p+1), d-block dblk = tid>>5.
  const int p    = tid & 31;
  const int dblk = tid >> 5;  // [0,8)
  const int pc   = p >> 2;
  const int cw   = (p & 3) * 4;
  unsigned voff = base + kvoff + (unsigned)(2 * p) * 2304u + 1536u + h64 + dblk * 8;

  auto vt_write = [&](char* W, const bf16x8& r0, const bf16x8& r1) {
#pragma unroll
    for (int j = 0; j < 8; ++j) {
      const int d = dblk * 8 + j;  // d&7 == j
      bf16x2 t2 = { r0[j], r1[j] };
      *(bf16x2*)(W + d * 128 + ((pc ^ j) << 4) + cw) = t2;
    }
  };

  float m = -1e30f, lsum = 0.f;   // lsum = lane-local PARTIAL row-sum
  f32x4 o[4] = {};

  // prologue: stage K tile 0 + V tile 0 into buf 0
  k_stage(0);
  {
    bf16x8 r0 = *(const bf16x8*)(qkv + voff);
    bf16x8 r1 = *(const bf16x8*)(qkv + voff + 2304);
    voff += VSTEP;
    vt_write(Vs, r0, r1);
  }
  __syncthreads();

  for (int t = 0; t < 16; ++t) {
    const int buf = t & 1;
    const bool pre = (t < 15);

    // (a) issue next tile's K stage (async -> LDS) and V reg loads early
    bf16x8 nr0, nr1;
    if (pre) {
      k_stage(buf ^ 1);
      nr0 = *(const bf16x8*)(qkv + voff);
      nr1 = *(const bf16x8*)(qkv + voff + 2304);
      voff += VSTEP;
    }

    // (b) S^T = K Q^T : A-frags from swizzled K LDS (row = f*16+l15, chunk kk*4+l4)
    const char* Kb = Ks + buf * 8192;
    f32x4 s[4];
    __builtin_amdgcn_s_setprio(1);
#pragma unroll
    for (int f = 0; f < 4; ++f) {
      const int row = f * 16 + l15;
      const char* krow = Kb + row * 128;
      bf16x8 k0 = *(const bf16x8*)(krow + (((0 + l4) ^ (row & 7)) << 4));
      bf16x8 k1 = *(const bf16x8*)(krow + (((4 + l4) ^ (row & 7)) << 4));
      f32x4 acc = {};
      acc = __builtin_amdgcn_mfma_f32_16x16x32_bf16(k0, qf[0], acc, 0, 0, 0);
      acc = __builtin_amdgcn_mfma_f32_16x16x32_bf16(k1, qf[1], acc, 0, 0, 0);
      s[f] = acc;
    }
    __builtin_amdgcn_s_setprio(0);

    // (c) shuffle-free steady-state softmax (exp2 domain)
    float tm = s[0][0];
#pragma unroll
    for (int f = 0; f < 4; ++f)
#pragma unroll
      for (int r = 0; r < 4; ++r) tm = fmaxf(tm, s[f][r]);

    if (__any(tm > m + 8.f)) {
      tm = fmaxf(tm, __shfl_xor(tm, 16));
      tm = fmaxf(tm, __shfl_xor(tm, 32));
      const float mn = fmaxf(m, tm);
      const float alpha = __builtin_amdgcn_exp2f(m - mn);
      m = mn;
      lsum *= alpha;
      f32x4 av;
#pragma unroll
      for (int r = 0; r < 4; ++r) av[r] = __shfl(alpha, l4 * 4 + r);
#pragma unroll
      for (int fd = 0; fd < 4; ++fd) o[fd] *= av;
    }

    // p = 2^(s - m); lane-local partial row-sum
    float rs = 0.f;
#pragma unroll
    for (int f = 0; f < 4; ++f)
#pragma unroll
      for (int r = 0; r < 4; ++r) {
        const float pv = __builtin_amdgcn_exp2f(s[f][r] - m);
        s[f][r] = pv;
        rs += pv;
      }
    lsum += rs;

    // P A-fragments (k-slot j of mfma kk -> kv = (kk*2+(j>>2))*16 + l4*4 + (j&3))
    bf16x8 pa[2];
#pragma unroll
    for (int kk = 0; kk < 2; ++kk)
#pragma unroll
      for (int j = 0; j < 8; ++j)
        pa[kk][j] = (bf16)s[kk * 2 + (j >> 2)][j & 3];

    // (e) O += P V : B-frags from swizzled Vt with the SAME permuted-kv mapping
    const char* Vb = Vs + buf * 8192;
    const int sub = (l4 & 1) * 8;
    __builtin_amdgcn_s_setprio(1);
#pragma unroll
    for (int kk = 0; kk < 2; ++kk) {
      const int cr0 = kk * 4 + (l4 >> 1);
#pragma unroll
      for (int fd = 0; fd < 4; ++fd) {
        const int d = fd * 16 + l15;
        const char* row = Vb + d * 128;
        bf16x4 lo = *(const bf16x4*)(row + ((cr0 ^ (d & 7)) << 4) + sub);
        bf16x4 hi = *(const bf16x4*)(row + (((cr0 + 2) ^ (d & 7)) << 4) + sub);
        bf16x8 vb = __builtin_shufflevector(lo, hi, 0, 1, 2, 3, 4, 5, 6, 7);
        o[fd] = __builtin_amdgcn_mfma_f32_16x16x32_bf16(pa[kk], vb, o[fd], 0, 0, 0);
      }
    }
    __builtin_amdgcn_s_setprio(0);

    // (d) late-write next V tile into the other buffer
    if (pre) vt_write(Vs + (buf ^ 1) * 8192, nr0, nr1);

    __syncthreads();
  }

  // epilogue: reduce the 4 lane-group partial row-sums (per q-col)
  lsum += __shfl_xor(lsum, 16);
  lsum += __shfl_xor(lsum, 32);

  // merge weight (exp2-domain): w = m + log2(lsum); one lane group writes
  if (l4 == 0) {
    const int token = b * 2048 + q0 + wv * 16 + l15;
    wbuf[(z * 4096 + token) * 12 + h] = m + __log2f(lsum);
  }

  // normalized partial O -> (z ? pb1 : ob)
  const float inv = 1.0f / lsum;
  f32x4 iv;
#pragma unroll
  for (int r = 0; r < 4; ++r) iv[r] = __shfl(inv, l4 * 4 + r);
  bf16* dst = z ? pb1 : ob;
  bf16* op = dst + ((long)(b * 2048 + q0 + wv * 16 + l4 * 4)) * 768 + h64 + l15;
#pragma unroll
  for (int fd = 0; fd < 4; ++fd)
#pragma unroll
    for (int r = 0; r < 4; ++r)
      op[(long)r * 768 + fd * 16] = (bf16)(o[fd][r] * iv[r]);
}

// ---------------- merge the two KV halves (in-place into ob) -----------------
// grid (32 qtiles, 24 bh), 256 thr: thread -> row = tid>>2, d-seg = (tid&3)*16.
__global__ __launch_bounds__(256) void attn_merge(bf16* __restrict__ ob,
                                                  const bf16* __restrict__ pb1,
                                                  const float* __restrict__ wbuf) {
  const int b   = blockIdx.y / 12;
  const int h   = blockIdx.y % 12;
  const int q0  = blockIdx.x * 64;
  const int row = threadIdx.x >> 2;
  const int ds  = (threadIdx.x & 3) * 16;
  const int token = b * 2048 + q0 + row;

  const float w0 = wbuf[token * 12 + h];
  const float w1 = wbuf[(4096 + token) * 12 + h];
  const float M  = fmaxf(w0, w1);
  const float e0 = __builtin_amdgcn_exp2f(w0 - M);
  const float e1 = __builtin_amdgcn_exp2f(w1 - M);
  const float inv = 1.0f / (e0 + e1);
  const float f0 = e0 * inv, f1 = e1 * inv;

  bf16* po = ob + (long)token * 768 + h * 64 + ds;
  const bf16* pp = pb1 + (long)token * 768 + h * 64 + ds;
#pragma unroll
  for (int half = 0; half < 2; ++half) {
    bf16x8 a = *(const bf16x8*)(po + half * 8);
    bf16x8 c = *(const bf16x8*)(pp + half * 8);
    bf16x8 r;
#pragma unroll
    for (int j = 0; j < 8; ++j) r[j] = (bf16)(f0 * (float)a[j] + f1 * (float)c[j]);
    *(bf16x8*)(po + half * 8) = r;
  }
}

// ---------------- launch ----------------
extern "C" void kernel_launch(void* const* d_in, const int* in_sizes, int n_in,
                              void* d_out, int out_size, void* d_ws, size_t ws_size,
                              hipStream_t stream) {
  const float* x  = (const float*)d_in[0];
  const float* wq = (const float*)d_in[1];
  const float* wp = (const float*)d_in[2];
  float* out = (float*)d_out;
  char* ws = (char*)d_ws;

  bf16* xb   = (bf16*)(ws + 0);
  bf16* wqb  = (bf16*)(ws + 6291456);
  bf16* wpb  = (bf16*)(ws + 9830400);
  bf16* qkvb = (bf16*)(ws + 11010048);
  bf16* ob   = (bf16*)(ws + 29884416);
  // attn partials reuse the xb/wqb region (dead after gemm1):
  bf16*  pb1  = (bf16*)(ws + 0);         // 6.29 MB (half-1 partial O)
  float* wbuf = (float*)(ws + 6291456);  // 393 KB (merge weights, both halves)

  cvt3<<<dim3(1024), dim3(256), 0, stream>>>(x, wq, wp, xb, wqb, wpb);
  // qkv = x @ Wqkv^T : M=4096 N=2304 K=768  (64x128 tiles -> 1152 blocks)
  gemm_nt<bf16, 64, 128><<<dim3(64 * 18), dim3(256), 0, stream>>>(
      xb, wqb, qkvb, 768, 768, 768, 2304, 64);
  attn_fwd<<<dim3(32, 24, 2), dim3(256), 0, stream>>>(qkvb, ob, pb1, wbuf);
  attn_merge<<<dim3(32, 24), dim3(256), 0, stream>>>(ob, pb1, wbuf);
  // out = attn_out @ Wproj^T : M=4096 N=768 K=768  (64x64 tiles -> 768 blocks)
  gemm_nt<float, 64, 64><<<dim3(64 * 12), dim3(256), 0, stream>>>(
      ob, wpb, out, 768, 768, 768, 768, 64);
}